// Round 16
// baseline (346.971 us; speedup 1.0000x reference)
//
#include <hip/hip_runtime.h>
#include <cstdint>
#include <cstddef>

typedef unsigned long long u64;
typedef unsigned int u32;
typedef u32 u32x4 __attribute__((ext_vector_type(4)));

#define AS1 __attribute__((address_space(1)))
#define AS3 __attribute__((address_space(3)))

constexpr int kB = 4;
constexpr int kNA = 20000;
constexpr int kV = 12000;
constexpr int kCAP = 5120;           // max candidates/batch with score>0.7 (actual ~4590)
constexpr int kW = kCAP / 64;        // 80 mask words per row
constexpr int kIC = 256;             // mask i-chunk
constexpr int kNCH = kCAP / kIC;     // chunks per column = 20
constexpr int kMAXOUT = 2000;
constexpr int kGPB = 20;             // scan groups per batch (4 blocks each)
constexpr int kMWG = kB * kW * kNCH / 4;   // mask WGs = 1600 (4 waves each)
constexpr float kIOU = 0.3f;
constexpr float kSCORE = 0.7f;

// Pure-SALU greedy over one 64-row block (free/kept in SGPRs; v_readlane pulls
// row t's diag word with an SGPR lane index).
static __device__ __forceinline__ u64 greedy64(u64 freeS, u32 d_lo, u32 d_hi) {
  u64 keptS;
  asm volatile(
      "s_mov_b64 s[40:41], %[free]\n\t"
      "s_mov_b64 s[42:43], 0\n\t"
      "GRD_%=:\n\t"
      "s_ff1_i32_b64 s44, s[40:41]\n\t"
      "s_cmp_eq_i32 s44, -1\n\t"
      "s_cbranch_scc1 GRDEND_%=\n\t"
      "s_bitset1_b64 s[42:43], s44\n\t"
      "s_bitset0_b64 s[40:41], s44\n\t"
      "v_readlane_b32 s46, %[dlo], s44\n\t"
      "v_readlane_b32 s47, %[dhi], s44\n\t"
      "s_nop 4\n\t"
      "s_andn2_b64 s[40:41], s[40:41], s[46:47]\n\t"
      "s_branch GRD_%=\n\t"
      "GRDEND_%=:\n\t"
      "s_mov_b64 %[kept], s[42:43]\n\t"
      : [kept] "=&s"(keptS)
      : [free] "s"(freeS), [dlo] "v"(d_lo), [dhi] "v"(d_hi)
      : "s40", "s41", "s42", "s43", "s44", "s45", "s46", "s47", "scc");
  return keptS;
}

__device__ __forceinline__ u64 waveOr64(u64 v) {
  v |= __shfl_xor((unsigned long long)v, 32, 64);
  v |= __shfl_xor((unsigned long long)v, 16, 64);
  v |= __shfl_xor((unsigned long long)v, 8, 64);
  v |= __shfl_xor((unsigned long long)v, 4, 64);
  v |= __shfl_xor((unsigned long long)v, 2, 64);
  v |= __shfl_xor((unsigned long long)v, 1, 64);
  return v;
}

__device__ __forceinline__ u64 readlane64u(u64 v, int l) {
  u32 lo = __builtin_amdgcn_readlane((u32)v, (u32)l);
  u32 hi = __builtin_amdgcn_readlane((u32)(v >> 32), (u32)l);
  return ((u64)hi << 32) | lo;
}

// ---------------- Stage A: gather + softmax + regress + filter ----------------
__global__ __launch_bounds__(256) void stage_score(
    const float* __restrict__ deltas, const float* __restrict__ logits,
    const float* __restrict__ anchors, const int* __restrict__ vidx,
    u32* __restrict__ counts, u64* __restrict__ keys,
    float* __restrict__ rec_y1, float* __restrict__ rec_y2,
    float* __restrict__ rec_l0, float* __restrict__ rec_l1) {
  int t = blockIdx.x * 256 + threadIdx.x;
  if (t >= kB * kV) return;
  int b = t / kV, i = t - b * kV;
  int lane = threadIdx.x & 63;
  int idx = vidx[i];
  float2 lg = *(const float2*)(logits + ((size_t)b * kNA + idx) * 2);
  // fg score = softmax prob of class 1 = sigmoid(l1 - l0)
  float score = 1.0f / (1.0f + expf(lg.x - lg.y));
  if (!(score > kSCORE)) return;   // non-candidates never keep, never suppress
  float2 dd = *(const float2*)(deltas + ((size_t)b * kNA + idx) * 2);
  float4 a = *(const float4*)(anchors + (size_t)i * 4);
  float h = a.w - a.y;
  float cy = (a.y + a.w) * 0.5f + (dd.x * 0.1f) * h;
  float hn = h * expf(dd.y * 0.2f);
  rec_y1[t] = cy - hn * 0.5f;
  rec_y2[t] = cy + hn * 0.5f;
  rec_l0[t] = lg.x;
  rec_l1[t] = lg.y;
  u64 act = __ballot(1);
  int b0 = (int)__builtin_amdgcn_readfirstlane((u32)b);
  u64 sameb = __ballot(b == b0);
  u64 grp = (b == b0) ? sameb : (act & ~sameb);
  u32 cnt = (u32)__popcll(grp);
  int lead = (int)__ffsll((unsigned long long)grp) - 1;
  u32 base = 0;
  if (lane == lead) base = atomicAdd(&counts[b], cnt);
  base = (u32)__shfl((int)base, lead, 64);
  u32 pos = base + (u32)__popcll(grp & ((1ULL << lane) - 1ULL));
  if (pos < kCAP) {
    // ascending order => descending score, ascending index tiebreak (stable argsort)
    u64 key = ((u64)(0xFFFFFFFFu - __float_as_uint(score)) << 32) | (u32)i;
    keys[(size_t)b * kCAP + pos] = key;
  }
}

// ---------------- Stage B: one-kernel rank sort + emit (80 blocks) ----------------
__global__ __launch_bounds__(256) void rank_sort_emit(
    const u32* __restrict__ counts, const u64* __restrict__ keys,
    const float* __restrict__ rec_y1, const float* __restrict__ rec_y2,
    const float* __restrict__ rec_l0, const float* __restrict__ rec_l1,
    const float* __restrict__ anchors,
    float4* __restrict__ sbox, float* __restrict__ sarea,
    float* __restrict__ ssc, float* __restrict__ sl0, float* __restrict__ sl1) {
  __shared__ u64 sk[kCAP];   // 40 KB
  int b = blockIdx.x / (kCAP / 256);
  int chunk = blockIdx.x % (kCAP / 256);
  int tid = threadIdx.x;
  int cnt = (int)min(counts[b], (u32)kCAP);
  for (int e = tid; e < kCAP; e += 256)
    sk[e] = (e < cnt) ? keys[(size_t)b * kCAP + e] : ~0ULL;
  __syncthreads();
  int s = chunk * 256 + tid;
  if (s >= cnt) return;
  u64 ks = sk[s];
  int rank = 0;
  for (int j = 0; j < kCAP; j += 8) {
#pragma unroll
    for (int u = 0; u < 8; ++u) rank += (sk[j + u] < ks) ? 1 : 0;
  }
  int i = (int)(u32)ks;
  float sc = __uint_as_float(0xFFFFFFFFu - (u32)(ks >> 32));
  float x1 = anchors[(size_t)i * 4 + 0], x2 = anchors[(size_t)i * 4 + 2];
  float y1 = rec_y1[b * kV + i], y2 = rec_y2[b * kV + i];
  size_t o = (size_t)b * kCAP + rank;
  sbox[o] = make_float4(x1, y1, x2, y2);
  sarea[o] = (x2 - x1) * (y2 - y1);
  ssc[o] = sc;
  sl0[o] = rec_l0[b * kV + i];
  sl1[o] = rec_l1[b * kV + i];
}

// ---------------- FUSED: wide mask + chain scan (v16) ---------------------------
// v12's fusion failed by SERIALIZING mask into the chain WGs; v16 keeps mask at
// full width (1600 WGs x 4 waves, v13 body) and co-dispatches the 80 chain WGs
// in the same launch, gated per mask-column:
//  * mask wave (bt,jb,ic): v13 body, then UNCONDITIONAL release fetch_add on
//    colcnt[bt][jb] (early-out waves still increment; target = 20).
//  * scan WG (bt,g): acquire-polls colcnt for columns 4g..4g+3 == 20, then runs
//    the v14 chain with NO LDS staging — all mask reads (16 reduce words/hop +
//    16 own-group words) are plain global loads of its OWN gated columns
//    (L2/L3-resident).  Publish/poll = v14's 8 flagged atomic words (best
//    measured; v15's single-flag variant regressed).
// Co-residency: kernel LDS = mask's 20KB -> all 1680 WGs fit on-chip
// simultaneously -> no dispatch deadlock by capacity.  Chain g=0 starts a few
// us into the kernel; mask's tail hides under the chain.
__global__ __launch_bounds__(256) void fused_mask_scan(
    const u32* __restrict__ counts,
    const float4* __restrict__ sbox, const float* __restrict__ sarea,
    u64* __restrict__ mask, u32* __restrict__ colcnt, u64* __restrict__ pub,
    const float* __restrict__ ssc, const float* __restrict__ sl0,
    const float* __restrict__ sl1, float* __restrict__ out) {
  __shared__ float4 sbc[4][kIC];   // 16 KB (mask role)
  __shared__ float sac[4][kIC];    // 4 KB
  const int bid = blockIdx.x;

  if (bid < kMWG) {
    // ======================= mask role (per wave) =======================
    int lane = threadIdx.x & 63;
    int wv = threadIdx.x >> 6;
    int gw = bid * 4 + wv;
    int bt = gw & 3;
    int rest = gw >> 2;
    int jb = rest % kW;
    int ic = rest / kW;
    int M = (int)min(counts[bt], (u32)kCAP);
    int W = (M + 63) >> 6;
    if (jb < W) {
      int ibeg = ic * kIC;
      int iend = min(min(M, jb * 64 + 64), ibeg + kIC);
      if (ibeg < iend) {
        const float4* pb = sbox + (size_t)bt * kCAP;
        const float* pa = sarea + (size_t)bt * kCAP;
        u64* mb = mask + (size_t)bt * ((size_t)kW * kCAP);
#pragma unroll
        for (int r = 0; r < kIC / 64; ++r) {
          int e = r * 64 + lane;
          sbc[wv][e] = pb[ibeg + e];
          sac[wv][e] = pa[ibeg + e];
        }
        int j = jb * 64 + lane;
        bool jv = (j < M);
        float4 bj = make_float4(0.f, 0.f, 0.f, 0.f);
        float aj = 0.f;
        if (jv) { bj = pb[j]; aj = pa[j]; }
        for (int b0 = ibeg; b0 < iend; b0 += 64) {
          int lim = min(iend - b0, 64);
          u64 mywm = 0;
#pragma unroll 4
          for (int k = 0; k < lim; ++k) {
            int e = b0 - ibeg + k;
            float4 bi = sbc[wv][e];
            float ai = sac[wv][e];
            float xx1 = fmaxf(bi.x, bj.x);
            float yy1 = fmaxf(bi.y, bj.y);
            float xx2 = fminf(bi.z, bj.z);
            float yy2 = fminf(bi.w, bj.w);
            float inter = fmaxf(xx2 - xx1, 0.0f) * fmaxf(yy2 - yy1, 0.0f);
            float iou = inter / (ai + aj - inter + 1e-10f); // IEEE div: bit-exact
            bool sup = jv && (j > b0 + k) && (iou > kIOU);
            u64 wm = __ballot(sup);
            if (k == lane) mywm = wm;
          }
          if (lane < lim)
            mb[(((size_t)(b0 >> 6)) * kW + jb) * 64 + lane] = mywm;
        }
      }
    }
    // release: this wave's stores drain before the counter reaches L3
    if (lane == 0)
      (void)__hip_atomic_fetch_add(&colcnt[bt * kW + jb], 1u, __ATOMIC_RELEASE,
                                   __HIP_MEMORY_SCOPE_AGENT);
    return;
  }

  // ======================= scan role (wave 0 of last 80 WGs) =======================
  if (threadIdx.x >= 64) return;
  const int sid = bid - kMWG;
  const int bt = sid & 3;
  const int g = sid >> 2;
  const int lane = threadIdx.x;
  const int M = (int)min(counts[bt], (u32)kCAP);
  const int W = (M + 63) >> 6;
  const int blk0 = 4 * g;
  if (blk0 >= W) return;          // monotonic: all earlier groups also valid
  const u64* mb = mask + (size_t)bt * ((size_t)kW * kCAP);
  u64* pp = pub + (size_t)(bt * kGPB) * 8;

  // gate: own columns 4g..4g+3 fully computed (acquire invalidates local caches)
#pragma unroll
  for (int c = 0; c < 4; ++c) {
    const u32* cp = &colcnt[bt * kW + 4 * g + c];
    while (__hip_atomic_load(cp, __ATOMIC_ACQUIRE, __HIP_MEMORY_SCOPE_AGENT) <
           (u32)kNCH)
      __builtin_amdgcn_s_sleep(16);
  }

  // own-column words for own blocks (diag = own[J][J]; folds = own[x][q>x])
  u64 own[4][4];
#pragma unroll
  for (int J = 0; J < 4; ++J)
#pragma unroll
    for (int q = 0; q < 4; ++q)
      own[J][q] = mb[((size_t)(blk0 + J) * kW + 4 * g + q) * 64 + lane];

  u64 acc0 = 0, acc1 = 0, acc2 = 0, acc3 = 0;
  u32 cum = 0;
  const u64* qa = pp + (size_t)lane * 2;              // words 2l, 2l+1
  const u64* qb = pp + 128 + (size_t)(lane & 15) * 2; // words 128+2l'
  int next = 0;
  while (next < g) {
    u32x4 ra, rb;
    asm volatile(
        "global_load_dwordx4 %0, %2, off sc0 sc1\n\t"
        "global_load_dwordx4 %1, %3, off sc0 sc1\n\t"
        "s_waitcnt vmcnt(0)"
        : "=&v"(ra), "=&v"(rb)
        : "v"(qa), "v"(qb)
        : "memory");
    u64 wA0 = ((u64)ra[1] << 32) | ra[0];
    u64 wA1 = ((u64)ra[3] << 32) | ra[2];
    u64 wB0 = ((u64)rb[1] << 32) | rb[0];
    u64 wB1 = ((u64)rb[3] << 32) | rb[2];
    u64 okA = __ballot(((wA0 & wA1) >> 63) != 0);
    u64 okB = __ballot(((wB0 & wB1) >> 63) != 0);
    int w = next;
    for (; w < g; ++w) {
      u64 km0, km1, km2, km3;
      if (w < 16) {
        if (((okA >> (4 * w)) & 0xFULL) != 0xFULL) break;
        int L = 4 * w;
        km0 = (u64)(u32)readlane64u(wA0, L)     | ((u64)(u32)readlane64u(wA1, L) << 32);
        km1 = (u64)(u32)readlane64u(wA0, L + 1) | ((u64)(u32)readlane64u(wA1, L + 1) << 32);
        km2 = (u64)(u32)readlane64u(wA0, L + 2) | ((u64)(u32)readlane64u(wA1, L + 2) << 32);
        km3 = (u64)(u32)readlane64u(wA0, L + 3) | ((u64)(u32)readlane64u(wA1, L + 3) << 32);
      } else {
        int L = 4 * (w - 16);
        if (((okB >> L) & 0xFULL) != 0xFULL) break;
        km0 = (u64)(u32)readlane64u(wB0, L)     | ((u64)(u32)readlane64u(wB1, L) << 32);
        km1 = (u64)(u32)readlane64u(wB0, L + 1) | ((u64)(u32)readlane64u(wB1, L + 1) << 32);
        km2 = (u64)(u32)readlane64u(wB0, L + 2) | ((u64)(u32)readlane64u(wB1, L + 2) << 32);
        km3 = (u64)(u32)readlane64u(wB0, L + 3) | ((u64)(u32)readlane64u(wB1, L + 3) << 32);
      }
      cum += (u32)__popcll(km0) + (u32)__popcll(km1) +
             (u32)__popcll(km2) + (u32)__popcll(km3);
      if (km0 | km1 | km2 | km3) {
        // 16 independent global loads of own-column words (gated, L2/L3-hot)
        u64 v[4][4];
#pragma unroll
        for (int c = 0; c < 4; ++c)
#pragma unroll
          for (int q = 0; q < 4; ++q)
            v[c][q] = mb[((size_t)(4 * w + c) * kW + 4 * g + q) * 64 + lane];
        u64 m0 = -(u64)((km0 >> lane) & 1ULL);
        u64 m1 = -(u64)((km1 >> lane) & 1ULL);
        u64 m2 = -(u64)((km2 >> lane) & 1ULL);
        u64 m3 = -(u64)((km3 >> lane) & 1ULL);
        acc0 |= waveOr64((v[0][0] & m0) | (v[1][0] & m1) | (v[2][0] & m2) | (v[3][0] & m3));
        acc1 |= waveOr64((v[0][1] & m0) | (v[1][1] & m1) | (v[2][1] & m2) | (v[3][1] & m3));
        acc2 |= waveOr64((v[0][2] & m0) | (v[1][2] & m1) | (v[2][2] & m2) | (v[3][2] & m3));
        acc3 |= waveOr64((v[0][3] & m0) | (v[1][3] & m1) | (v[2][3] & m2) | (v[3][3] & m3));
      }
    }
    next = w;
    if (next < g) __builtin_amdgcn_s_sleep(8);
  }

  // own-group serial: greedy per block, fold kept into later words
  u64 km[4];
  u32 cums[4];
#define OWN_BLOCK(J, ACC)                                                     \
  {                                                                           \
    const int blk = blk0 + (J);                                               \
    cums[J] = cum;                                                            \
    u64 k = 0;                                                                \
    if (blk < W && (int)cum < kMAXOUT) {                                      \
      int remn = M - blk * 64;                                                \
      u64 validm = (remn >= 64) ? ~0ULL : ((1ULL << remn) - 1ULL);            \
      u64 freeb = ~(ACC)&validm;                                              \
      u32 flo = __builtin_amdgcn_readfirstlane((u32)freeb);                   \
      u32 fhi = __builtin_amdgcn_readfirstlane((u32)(freeb >> 32));           \
      u64 diag = own[J][J];                                                   \
      k = greedy64(((u64)fhi << 32) | flo, (u32)diag, (u32)(diag >> 32));     \
    }                                                                         \
    km[J] = k;                                                                \
    cum += (u32)__popcll(k);                                                  \
  }
  OWN_BLOCK(0, acc0)
  if (km[0]) {
    u64 m = -(u64)((km[0] >> lane) & 1ULL);
    acc1 |= waveOr64(own[0][1] & m);
    acc2 |= waveOr64(own[0][2] & m);
    acc3 |= waveOr64(own[0][3] & m);
  }
  OWN_BLOCK(1, acc1)
  if (km[1]) {
    u64 m = -(u64)((km[1] >> lane) & 1ULL);
    acc2 |= waveOr64(own[1][2] & m);
    acc3 |= waveOr64(own[1][3] & m);
  }
  OWN_BLOCK(2, acc2)
  if (km[2]) {
    u64 m = -(u64)((km[2] >> lane) & 1ULL);
    acc3 |= waveOr64(own[2][3] & m);
  }
  OWN_BLOCK(3, acc3)
#undef OWN_BLOCK

  // publish FIRST (critical path): v14's 8 fire-and-forget flagged atomic words
  if (lane == 0) {
    const u64 F = 1ULL << 63;
#pragma unroll
    for (int c = 0; c < 4; ++c) {
      (void)__hip_atomic_fetch_or(&pp[(size_t)g * 8 + 2 * c], F | (u64)(u32)km[c],
                                  __ATOMIC_RELAXED, __HIP_MEMORY_SCOPE_AGENT);
      (void)__hip_atomic_fetch_or(&pp[(size_t)g * 8 + 2 * c + 1],
                                  F | (u64)(u32)(km[c] >> 32),
                                  __ATOMIC_RELAXED, __HIP_MEMORY_SCOPE_AGENT);
    }
  }

  // fused output scatter (off critical path)
  float* boxes = out;                                    // [B][2000][5]
  float* bscores = out + (size_t)kB * kMAXOUT * 5;       // [B][2000][2]
  float* blogits = out + (size_t)kB * kMAXOUT * 7;       // [B][2000][3]
  auto emit = [&](int i, int rank) {
    size_t o = (size_t)bt * kCAP + i;
    float4 bx = sbox[o];
    size_t t = (size_t)bt * kMAXOUT + rank;
    boxes[t * 5 + 0] = bx.x;
    boxes[t * 5 + 1] = bx.y;
    boxes[t * 5 + 2] = bx.z;
    boxes[t * 5 + 3] = bx.w;
    boxes[t * 5 + 4] = 1.0f;
    bscores[t * 2 + 0] = ssc[o];
    bscores[t * 2 + 1] = 1.0f;
    blogits[t * 3 + 0] = sl0[o];
    blogits[t * 3 + 1] = sl1[o];
    blogits[t * 3 + 2] = 1.0f;
  };
#pragma unroll
  for (int c = 0; c < 4; ++c) {
    if ((km[c] >> lane) & 1ULL) {
      int rank = (int)cums[c] + (int)__popcll(km[c] & ((1ULL << lane) - 1ULL));
      if (rank < kMAXOUT) emit((blk0 + c) * 64 + lane, rank);
    }
  }
}

extern "C" void kernel_launch(void* const* d_in, const int* in_sizes, int n_in,
                              void* d_out, int out_size, void* d_ws, size_t ws_size,
                              hipStream_t stream) {
  const float* deltas = (const float*)d_in[0];
  // d_in[1] = side_deltas: dead (USE_SIDE_REFINE=False; cx/dx unused for output)
  const float* logits = (const float*)d_in[2];
  const float* anchors = (const float*)d_in[3];
  const int* vidx = (const int*)d_in[4];
  float* out = (float*)d_out;

  char* p = (char*)d_ws;
  auto take = [&](size_t bytes) -> char* {
    char* r = p;
    p += (bytes + 255) & ~(size_t)255;
    return r;
  };
  // counts + pub + colcnt contiguous: one memset zeroes all (256+5120+1280)
  u32* counts = (u32*)take(kB * sizeof(u32));                       // +0,    256B
  u64* pub = (u64*)take((size_t)kB * kGPB * 8 * sizeof(u64));       // +256,  5120B
  u32* colcnt = (u32*)take((size_t)kB * kW * sizeof(u32));          // +5376, 1280B
  u64* keys = (u64*)take((size_t)kB * kCAP * sizeof(u64));
  float* rec_y1 = (float*)take((size_t)kB * kV * sizeof(float));
  float* rec_y2 = (float*)take((size_t)kB * kV * sizeof(float));
  float* rec_l0 = (float*)take((size_t)kB * kV * sizeof(float));
  float* rec_l1 = (float*)take((size_t)kB * kV * sizeof(float));
  float4* sbox = (float4*)take((size_t)kB * kCAP * sizeof(float4));
  float* sarea = (float*)take((size_t)kB * kCAP * sizeof(float));
  float* ssc = (float*)take((size_t)kB * kCAP * sizeof(float));
  float* sl0 = (float*)take((size_t)kB * kCAP * sizeof(float));
  float* sl1 = (float*)take((size_t)kB * kCAP * sizeof(float));
  u64* mask = (u64*)take((size_t)kB * kCAP * kW * sizeof(u64) + 4096);

  (void)hipMemsetAsync(out, 0, (size_t)out_size * sizeof(float), stream);
  (void)hipMemsetAsync(counts, 0, 6656, stream);   // counts + pub + colcnt

  stage_score<<<(kB * kV + 255) / 256, 256, 0, stream>>>(
      deltas, logits, anchors, vidx, counts, keys, rec_y1, rec_y2, rec_l0, rec_l1);
  rank_sort_emit<<<kB * (kCAP / 256), 256, 0, stream>>>(
      counts, keys, rec_y1, rec_y2, rec_l0, rec_l1, anchors,
      sbox, sarea, ssc, sl0, sl1);
  fused_mask_scan<<<kMWG + kB * kGPB, 256, 0, stream>>>(
      counts, sbox, sarea, mask, colcnt, pub, ssc, sl0, sl1, out);
}

// Round 17
// 346.540 us; speedup vs baseline: 1.0012x; 1.0012x over previous
//
#include <hip/hip_runtime.h>
#include <cstdint>
#include <cstddef>

typedef unsigned long long u64;
typedef unsigned int u32;
typedef u32 u32x4 __attribute__((ext_vector_type(4)));

#define AS1 __attribute__((address_space(1)))
#define AS3 __attribute__((address_space(3)))

constexpr int kB = 4;
constexpr int kNA = 20000;
constexpr int kV = 12000;
constexpr int kCAP = 5120;           // max candidates/batch with score>0.7 (actual ~4590)
constexpr int kW = kCAP / 64;        // 80 mask words per row
constexpr int kIC = 256;             // mask i-chunk
constexpr int kNCH = kCAP / kIC;     // chunks per column = 20
constexpr int kMAXOUT = 2000;
constexpr int kGPB = 20;             // scan groups per batch (4 blocks each)
constexpr int kSWG = kB * kGPB;      // scan WGs = 80 (FIRST in grid)
constexpr int kMWG = kB * kW * kNCH / 4;   // mask WGs = 1600 (4 waves each)
constexpr float kIOU = 0.3f;
constexpr float kSCORE = 0.7f;

// Pure-SALU greedy over one 64-row block (free/kept in SGPRs; v_readlane pulls
// row t's diag word with an SGPR lane index).
static __device__ __forceinline__ u64 greedy64(u64 freeS, u32 d_lo, u32 d_hi) {
  u64 keptS;
  asm volatile(
      "s_mov_b64 s[40:41], %[free]\n\t"
      "s_mov_b64 s[42:43], 0\n\t"
      "GRD_%=:\n\t"
      "s_ff1_i32_b64 s44, s[40:41]\n\t"
      "s_cmp_eq_i32 s44, -1\n\t"
      "s_cbranch_scc1 GRDEND_%=\n\t"
      "s_bitset1_b64 s[42:43], s44\n\t"
      "s_bitset0_b64 s[40:41], s44\n\t"
      "v_readlane_b32 s46, %[dlo], s44\n\t"
      "v_readlane_b32 s47, %[dhi], s44\n\t"
      "s_nop 4\n\t"
      "s_andn2_b64 s[40:41], s[40:41], s[46:47]\n\t"
      "s_branch GRD_%=\n\t"
      "GRDEND_%=:\n\t"
      "s_mov_b64 %[kept], s[42:43]\n\t"
      : [kept] "=&s"(keptS)
      : [free] "s"(freeS), [dlo] "v"(d_lo), [dhi] "v"(d_hi)
      : "s40", "s41", "s42", "s43", "s44", "s45", "s46", "s47", "scc");
  return keptS;
}

__device__ __forceinline__ u64 waveOr64(u64 v) {
  v |= __shfl_xor((unsigned long long)v, 32, 64);
  v |= __shfl_xor((unsigned long long)v, 16, 64);
  v |= __shfl_xor((unsigned long long)v, 8, 64);
  v |= __shfl_xor((unsigned long long)v, 4, 64);
  v |= __shfl_xor((unsigned long long)v, 2, 64);
  v |= __shfl_xor((unsigned long long)v, 1, 64);
  return v;
}

__device__ __forceinline__ u64 readlane64u(u64 v, int l) {
  u32 lo = __builtin_amdgcn_readlane((u32)v, (u32)l);
  u32 hi = __builtin_amdgcn_readlane((u32)(v >> 32), (u32)l);
  return ((u64)hi << 32) | lo;
}

// ---------------- Stage A: gather + softmax + regress + filter ----------------
__global__ __launch_bounds__(256) void stage_score(
    const float* __restrict__ deltas, const float* __restrict__ logits,
    const float* __restrict__ anchors, const int* __restrict__ vidx,
    u32* __restrict__ counts, u64* __restrict__ keys,
    float* __restrict__ rec_y1, float* __restrict__ rec_y2,
    float* __restrict__ rec_l0, float* __restrict__ rec_l1) {
  int t = blockIdx.x * 256 + threadIdx.x;
  if (t >= kB * kV) return;
  int b = t / kV, i = t - b * kV;
  int lane = threadIdx.x & 63;
  int idx = vidx[i];
  float2 lg = *(const float2*)(logits + ((size_t)b * kNA + idx) * 2);
  // fg score = softmax prob of class 1 = sigmoid(l1 - l0)
  float score = 1.0f / (1.0f + expf(lg.x - lg.y));
  if (!(score > kSCORE)) return;   // non-candidates never keep, never suppress
  float2 dd = *(const float2*)(deltas + ((size_t)b * kNA + idx) * 2);
  float4 a = *(const float4*)(anchors + (size_t)i * 4);
  float h = a.w - a.y;
  float cy = (a.y + a.w) * 0.5f + (dd.x * 0.1f) * h;
  float hn = h * expf(dd.y * 0.2f);
  rec_y1[t] = cy - hn * 0.5f;
  rec_y2[t] = cy + hn * 0.5f;
  rec_l0[t] = lg.x;
  rec_l1[t] = lg.y;
  u64 act = __ballot(1);
  int b0 = (int)__builtin_amdgcn_readfirstlane((u32)b);
  u64 sameb = __ballot(b == b0);
  u64 grp = (b == b0) ? sameb : (act & ~sameb);
  u32 cnt = (u32)__popcll(grp);
  int lead = (int)__ffsll((unsigned long long)grp) - 1;
  u32 base = 0;
  if (lane == lead) base = atomicAdd(&counts[b], cnt);
  base = (u32)__shfl((int)base, lead, 64);
  u32 pos = base + (u32)__popcll(grp & ((1ULL << lane) - 1ULL));
  if (pos < kCAP) {
    // ascending order => descending score, ascending index tiebreak (stable argsort)
    u64 key = ((u64)(0xFFFFFFFFu - __float_as_uint(score)) << 32) | (u32)i;
    keys[(size_t)b * kCAP + pos] = key;
  }
}

// ---------------- Stage B: one-kernel rank sort + emit (80 blocks) ----------------
__global__ __launch_bounds__(256) void rank_sort_emit(
    const u32* __restrict__ counts, const u64* __restrict__ keys,
    const float* __restrict__ rec_y1, const float* __restrict__ rec_y2,
    const float* __restrict__ rec_l0, const float* __restrict__ rec_l1,
    const float* __restrict__ anchors,
    float4* __restrict__ sbox, float* __restrict__ sarea,
    float* __restrict__ ssc, float* __restrict__ sl0, float* __restrict__ sl1) {
  __shared__ u64 sk[kCAP];   // 40 KB
  int b = blockIdx.x / (kCAP / 256);
  int chunk = blockIdx.x % (kCAP / 256);
  int tid = threadIdx.x;
  int cnt = (int)min(counts[b], (u32)kCAP);
  for (int e = tid; e < kCAP; e += 256)
    sk[e] = (e < cnt) ? keys[(size_t)b * kCAP + e] : ~0ULL;
  __syncthreads();
  int s = chunk * 256 + tid;
  if (s >= cnt) return;
  u64 ks = sk[s];
  int rank = 0;
  for (int j = 0; j < kCAP; j += 8) {
#pragma unroll
    for (int u = 0; u < 8; ++u) rank += (sk[j + u] < ks) ? 1 : 0;
  }
  int i = (int)(u32)ks;
  float sc = __uint_as_float(0xFFFFFFFFu - (u32)(ks >> 32));
  float x1 = anchors[(size_t)i * 4 + 0], x2 = anchors[(size_t)i * 4 + 2];
  float y1 = rec_y1[b * kV + i], y2 = rec_y2[b * kV + i];
  size_t o = (size_t)b * kCAP + rank;
  sbox[o] = make_float4(x1, y1, x2, y2);
  sarea[o] = (x2 - x1) * (y2 - y1);
  ssc[o] = sc;
  sl0[o] = rec_l0[b * kV + i];
  sl1[o] = rec_l1[b * kV + i];
}

// ---------------- FUSED: wide mask + chain scan (v17) ---------------------------
// v16's overlap failed from TWO dispatch-order bugs, both fixed here:
//  (1) COLUMN-MAJOR mask decode (jb = gw/80): a column's 20 chunks are 5
//      consecutive WGs -> columns 0..3 done within the first ~20 mask WGs
//      (v16's chunk-major put column 0's last chunk at bid ~1520 -> gate
//      opened only after nearly all mask work).
//  (2) SCAN WGs FIRST in the grid (bids 0..79): resident and polling from
//      t=0 (v16 put them last -> not dispatched until mask mostly retired).
//  (3) PREFETCH: hop mask-reads' addresses depend only on (w,g) — validity
//      comes from the column gate, NOT the chain mailbox — so pv[4][4] for
//      group `next` is issued before/during the poll (drained by the poll's
//      vmcnt(0)); own-block words staged via 8 global_load_lds into the
//      scan-role LDS (zero VGPR cost).  Removes v16's exposed per-hop
//      dependent-load latency.
// Publish/poll = v14's 8 flagged atomic words (best measured).
__global__ __launch_bounds__(256) void fused_mask_scan(
    const u32* __restrict__ counts,
    const float4* __restrict__ sbox, const float* __restrict__ sarea,
    u64* __restrict__ mask, u32* __restrict__ colcnt, u64* __restrict__ pub,
    const float* __restrict__ ssc, const float* __restrict__ sl0,
    const float* __restrict__ sl1, float* __restrict__ out) {
  __shared__ __align__(16) char smem[20480];   // mask: 16K boxes + 4K areas | scan: 8K own-words
  const int bid = blockIdx.x;

  if (bid >= kSWG) {
    // ======================= mask role (per wave) =======================
    float4* sbc = (float4*)smem;               // [4][kIC]
    float* sac = (float*)(smem + 16384);       // [4][kIC]
    int lane = threadIdx.x & 63;
    int wv = threadIdx.x >> 6;
    int gw = (bid - kSWG) * 4 + wv;
    int jb = gw / (kB * kNCH);                 // column-major: jb slowest
    int rest = gw - jb * (kB * kNCH);
    int bt = rest & 3;
    int ic = rest >> 2;
    int M = (int)min(counts[bt], (u32)kCAP);
    int W = (M + 63) >> 6;
    if (jb < W) {
      int ibeg = ic * kIC;
      int iend = min(min(M, jb * 64 + 64), ibeg + kIC);
      if (ibeg < iend) {
        const float4* pb = sbox + (size_t)bt * kCAP;
        const float* pa = sarea + (size_t)bt * kCAP;
        u64* mb = mask + (size_t)bt * ((size_t)kW * kCAP);
#pragma unroll
        for (int r = 0; r < kIC / 64; ++r) {
          int e = r * 64 + lane;
          sbc[wv * kIC + e] = pb[ibeg + e];
          sac[wv * kIC + e] = pa[ibeg + e];
        }
        int j = jb * 64 + lane;
        bool jv = (j < M);
        float4 bj = make_float4(0.f, 0.f, 0.f, 0.f);
        float aj = 0.f;
        if (jv) { bj = pb[j]; aj = pa[j]; }
        for (int b0 = ibeg; b0 < iend; b0 += 64) {
          int lim = min(iend - b0, 64);
          u64 mywm = 0;
#pragma unroll 4
          for (int k = 0; k < lim; ++k) {
            int e = b0 - ibeg + k;
            float4 bi = sbc[wv * kIC + e];
            float ai = sac[wv * kIC + e];
            float xx1 = fmaxf(bi.x, bj.x);
            float yy1 = fmaxf(bi.y, bj.y);
            float xx2 = fminf(bi.z, bj.z);
            float yy2 = fminf(bi.w, bj.w);
            float inter = fmaxf(xx2 - xx1, 0.0f) * fmaxf(yy2 - yy1, 0.0f);
            float iou = inter / (ai + aj - inter + 1e-10f); // IEEE div: bit-exact
            bool sup = jv && (j > b0 + k) && (iou > kIOU);
            u64 wm = __ballot(sup);
            if (k == lane) mywm = wm;
          }
          if (lane < lim)
            mb[(((size_t)(b0 >> 6)) * kW + jb) * 64 + lane] = mywm;
        }
      }
    }
    // release: this wave's stores drain before the counter update is visible
    if (lane == 0)
      (void)__hip_atomic_fetch_add(&colcnt[bt * kW + jb], 1u, __ATOMIC_RELEASE,
                                   __HIP_MEMORY_SCOPE_AGENT);
    return;
  }

  // ======================= scan role (wave 0 of first 80 WGs) =======================
  if (threadIdx.x >= 64) return;
  u64* ownl = (u64*)smem;                      // 8 slots x 128 u64 = 8 KB
  const int bt = bid & 3;
  const int g = bid >> 2;
  const int lane = threadIdx.x;
  const int M = (int)min(counts[bt], (u32)kCAP);
  const int W = (M + 63) >> 6;
  const int blk0 = 4 * g;
  if (blk0 >= W) return;          // monotonic: all earlier groups also valid
  const u64* mb = mask + (size_t)bt * ((size_t)kW * kCAP);
  u64* pp = pub + (size_t)(bt * kGPB) * 8;

  // gate: own columns 4g..4g+3 fully computed (acquire invalidates local caches)
#pragma unroll
  for (int c = 0; c < 4; ++c) {
    const u32* cp = &colcnt[bt * kW + 4 * g + c];
    while (__hip_atomic_load(cp, __ATOMIC_ACQUIRE, __HIP_MEMORY_SCOPE_AGENT) <
           (u32)kNCH)
      __builtin_amdgcn_s_sleep(16);
  }

  // stage own-block words (blk0+J, word-pair 4g+2c) into LDS: 8 x 1KB dense
#pragma unroll
  for (int J = 0; J < 4; ++J)
#pragma unroll
    for (int c = 0; c < 2; ++c)
      __builtin_amdgcn_global_load_lds(
          (const AS1 u32*)(mb + ((size_t)(blk0 + J) * kW + 4 * g + 2 * c) * 64 +
                           (size_t)lane * 2),
          (AS3 u32*)&ownl[(J * 2 + c) * 128], 16, 0, 0);
  // ownw(J,q) = ownl[(J*2 + (q>>1))*128 + (q&1)*64 + lane]

  u64 acc0 = 0, acc1 = 0, acc2 = 0, acc3 = 0;
  u32 cum = 0;
  const u64* qa = pp + (size_t)lane * 2;              // words 2l, 2l+1
  const u64* qb = pp + 128 + (size_t)(lane & 15) * 2; // words 128+2l'
  u64 pv[4][4];
  auto issuePf = [&](int w) {
#pragma unroll
    for (int c = 0; c < 4; ++c)
#pragma unroll
      for (int q = 0; q < 4; ++q)
        pv[c][q] = mb[((size_t)(4 * w + c) * kW + 4 * g + q) * 64 + lane];
  };
  int next = 0;
  if (g > 0) issuePf(0);
  while (next < g) {
    u32x4 ra, rb;
    asm volatile(
        "global_load_dwordx4 %0, %2, off sc0 sc1\n\t"
        "global_load_dwordx4 %1, %3, off sc0 sc1\n\t"
        "s_waitcnt vmcnt(0)"
        : "=&v"(ra), "=&v"(rb)
        : "v"(qa), "v"(qb)
        : "memory");
    u64 wA0 = ((u64)ra[1] << 32) | ra[0];
    u64 wA1 = ((u64)ra[3] << 32) | ra[2];
    u64 wB0 = ((u64)rb[1] << 32) | rb[0];
    u64 wB1 = ((u64)rb[3] << 32) | rb[2];
    u64 okA = __ballot(((wA0 & wA1) >> 63) != 0);
    u64 okB = __ballot(((wB0 & wB1) >> 63) != 0);
    bool adv = false;
    while (next < g) {
      const int w = next;
      u64 km0, km1, km2, km3;
      if (w < 16) {
        if (((okA >> (4 * w)) & 0xFULL) != 0xFULL) break;
        int L = 4 * w;
        km0 = (u64)(u32)readlane64u(wA0, L)     | ((u64)(u32)readlane64u(wA1, L) << 32);
        km1 = (u64)(u32)readlane64u(wA0, L + 1) | ((u64)(u32)readlane64u(wA1, L + 1) << 32);
        km2 = (u64)(u32)readlane64u(wA0, L + 2) | ((u64)(u32)readlane64u(wA1, L + 2) << 32);
        km3 = (u64)(u32)readlane64u(wA0, L + 3) | ((u64)(u32)readlane64u(wA1, L + 3) << 32);
      } else {
        int L = 4 * (w - 16);
        if (((okB >> L) & 0xFULL) != 0xFULL) break;
        km0 = (u64)(u32)readlane64u(wB0, L)     | ((u64)(u32)readlane64u(wB1, L) << 32);
        km1 = (u64)(u32)readlane64u(wB0, L + 1) | ((u64)(u32)readlane64u(wB1, L + 1) << 32);
        km2 = (u64)(u32)readlane64u(wB0, L + 2) | ((u64)(u32)readlane64u(wB1, L + 2) << 32);
        km3 = (u64)(u32)readlane64u(wB0, L + 3) | ((u64)(u32)readlane64u(wB1, L + 3) << 32);
      }
      cum += (u32)__popcll(km0) + (u32)__popcll(km1) +
             (u32)__popcll(km2) + (u32)__popcll(km3);
      if (km0 | km1 | km2 | km3) {
        u64 m0 = -(u64)((km0 >> lane) & 1ULL);
        u64 m1 = -(u64)((km1 >> lane) & 1ULL);
        u64 m2 = -(u64)((km2 >> lane) & 1ULL);
        u64 m3 = -(u64)((km3 >> lane) & 1ULL);
        acc0 |= waveOr64((pv[0][0] & m0) | (pv[1][0] & m1) | (pv[2][0] & m2) | (pv[3][0] & m3));
        acc1 |= waveOr64((pv[0][1] & m0) | (pv[1][1] & m1) | (pv[2][1] & m2) | (pv[3][1] & m3));
        acc2 |= waveOr64((pv[0][2] & m0) | (pv[1][2] & m1) | (pv[2][2] & m2) | (pv[3][2] & m3));
        acc3 |= waveOr64((pv[0][3] & m0) | (pv[1][3] & m1) | (pv[2][3] & m2) | (pv[3][3] & m3));
      }
      ++next;
      if (next < g) issuePf(next);   // overlaps with flag re-check / next poll
      adv = true;
    }
    if (next < g && !adv) __builtin_amdgcn_s_sleep(8);
  }
  __builtin_amdgcn_s_waitcnt(0x0070);   // g==0 path: drain own-LDS stage loads

  // own-group serial: greedy per block, fold kept into later words (LDS reads)
  u64 km[4];
  u32 cums[4];
  auto ownw = [&](int J, int q) -> u64 {
    return ownl[(J * 2 + (q >> 1)) * 128 + (q & 1) * 64 + lane];
  };
#define OWN_BLOCK(J, ACC)                                                     \
  {                                                                           \
    const int blk = blk0 + (J);                                               \
    cums[J] = cum;                                                            \
    u64 k = 0;                                                                \
    if (blk < W && (int)cum < kMAXOUT) {                                      \
      int remn = M - blk * 64;                                                \
      u64 validm = (remn >= 64) ? ~0ULL : ((1ULL << remn) - 1ULL);            \
      u64 freeb = ~(ACC)&validm;                                              \
      u32 flo = __builtin_amdgcn_readfirstlane((u32)freeb);                   \
      u32 fhi = __builtin_amdgcn_readfirstlane((u32)(freeb >> 32));           \
      u64 diag = ownw(J, J);                                                  \
      k = greedy64(((u64)fhi << 32) | flo, (u32)diag, (u32)(diag >> 32));     \
    }                                                                         \
    km[J] = k;                                                                \
    cum += (u32)__popcll(k);                                                  \
  }
  OWN_BLOCK(0, acc0)
  if (km[0]) {
    u64 m = -(u64)((km[0] >> lane) & 1ULL);
    acc1 |= waveOr64(ownw(0, 1) & m);
    acc2 |= waveOr64(ownw(0, 2) & m);
    acc3 |= waveOr64(ownw(0, 3) & m);
  }
  OWN_BLOCK(1, acc1)
  if (km[1]) {
    u64 m = -(u64)((km[1] >> lane) & 1ULL);
    acc2 |= waveOr64(ownw(1, 2) & m);
    acc3 |= waveOr64(ownw(1, 3) & m);
  }
  OWN_BLOCK(2, acc2)
  if (km[2]) {
    u64 m = -(u64)((km[2] >> lane) & 1ULL);
    acc3 |= waveOr64(ownw(2, 3) & m);
  }
  OWN_BLOCK(3, acc3)
#undef OWN_BLOCK

  // publish FIRST (critical path): v14's 8 fire-and-forget flagged atomic words
  if (lane == 0) {
    const u64 F = 1ULL << 63;
#pragma unroll
    for (int c = 0; c < 4; ++c) {
      (void)__hip_atomic_fetch_or(&pp[(size_t)g * 8 + 2 * c], F | (u64)(u32)km[c],
                                  __ATOMIC_RELAXED, __HIP_MEMORY_SCOPE_AGENT);
      (void)__hip_atomic_fetch_or(&pp[(size_t)g * 8 + 2 * c + 1],
                                  F | (u64)(u32)(km[c] >> 32),
                                  __ATOMIC_RELAXED, __HIP_MEMORY_SCOPE_AGENT);
    }
  }

  // fused output scatter (off critical path)
  float* boxes = out;                                    // [B][2000][5]
  float* bscores = out + (size_t)kB * kMAXOUT * 5;       // [B][2000][2]
  float* blogits = out + (size_t)kB * kMAXOUT * 7;       // [B][2000][3]
  auto emit = [&](int i, int rank) {
    size_t o = (size_t)bt * kCAP + i;
    float4 bx = sbox[o];
    size_t t = (size_t)bt * kMAXOUT + rank;
    boxes[t * 5 + 0] = bx.x;
    boxes[t * 5 + 1] = bx.y;
    boxes[t * 5 + 2] = bx.z;
    boxes[t * 5 + 3] = bx.w;
    boxes[t * 5 + 4] = 1.0f;
    bscores[t * 2 + 0] = ssc[o];
    bscores[t * 2 + 1] = 1.0f;
    blogits[t * 3 + 0] = sl0[o];
    blogits[t * 3 + 1] = sl1[o];
    blogits[t * 3 + 2] = 1.0f;
  };
#pragma unroll
  for (int c = 0; c < 4; ++c) {
    if ((km[c] >> lane) & 1ULL) {
      int rank = (int)cums[c] + (int)__popcll(km[c] & ((1ULL << lane) - 1ULL));
      if (rank < kMAXOUT) emit((blk0 + c) * 64 + lane, rank);
    }
  }
}

extern "C" void kernel_launch(void* const* d_in, const int* in_sizes, int n_in,
                              void* d_out, int out_size, void* d_ws, size_t ws_size,
                              hipStream_t stream) {
  const float* deltas = (const float*)d_in[0];
  // d_in[1] = side_deltas: dead (USE_SIDE_REFINE=False; cx/dx unused for output)
  const float* logits = (const float*)d_in[2];
  const float* anchors = (const float*)d_in[3];
  const int* vidx = (const int*)d_in[4];
  float* out = (float*)d_out;

  char* p = (char*)d_ws;
  auto take = [&](size_t bytes) -> char* {
    char* r = p;
    p += (bytes + 255) & ~(size_t)255;
    return r;
  };
  // counts + pub + colcnt contiguous: one memset zeroes all (256+5120+1280)
  u32* counts = (u32*)take(kB * sizeof(u32));                       // +0,    256B
  u64* pub = (u64*)take((size_t)kB * kGPB * 8 * sizeof(u64));       // +256,  5120B
  u32* colcnt = (u32*)take((size_t)kB * kW * sizeof(u32));          // +5376, 1280B
  u64* keys = (u64*)take((size_t)kB * kCAP * sizeof(u64));
  float* rec_y1 = (float*)take((size_t)kB * kV * sizeof(float));
  float* rec_y2 = (float*)take((size_t)kB * kV * sizeof(float));
  float* rec_l0 = (float*)take((size_t)kB * kV * sizeof(float));
  float* rec_l1 = (float*)take((size_t)kB * kV * sizeof(float));
  float4* sbox = (float4*)take((size_t)kB * kCAP * sizeof(float4));
  float* sarea = (float*)take((size_t)kB * kCAP * sizeof(float));
  float* ssc = (float*)take((size_t)kB * kCAP * sizeof(float));
  float* sl0 = (float*)take((size_t)kB * kCAP * sizeof(float));
  float* sl1 = (float*)take((size_t)kB * kCAP * sizeof(float));
  u64* mask = (u64*)take((size_t)kB * kCAP * kW * sizeof(u64) + 4096);

  (void)hipMemsetAsync(out, 0, (size_t)out_size * sizeof(float), stream);
  (void)hipMemsetAsync(counts, 0, 6656, stream);   // counts + pub + colcnt

  stage_score<<<(kB * kV + 255) / 256, 256, 0, stream>>>(
      deltas, logits, anchors, vidx, counts, keys, rec_y1, rec_y2, rec_l0, rec_l1);
  rank_sort_emit<<<kB * (kCAP / 256), 256, 0, stream>>>(
      counts, keys, rec_y1, rec_y2, rec_l0, rec_l1, anchors,
      sbox, sarea, ssc, sl0, sl1);
  fused_mask_scan<<<kSWG + kMWG, 256, 0, stream>>>(
      counts, sbox, sarea, mask, colcnt, pub, ssc, sl0, sl1, out);
}